// Round 15
// baseline (240.328 us; speedup 1.0000x reference)
//
#include <hip/hip_runtime.h>
#include <stdint.h>

#define NG 4
#define NK 160
#define GD 128
#define ED 512
#define BB 16
#define TT 4096
#define BK 32
#define BTOK 256
static constexpr size_t ZSZ = (size_t)BB * ED * TT;           // 33554432

typedef float f32x4 __attribute__((ext_vector_type(4)));

// d_out FLOAT32: [0,ZSZ) z_q | [ZSZ] loss | codes after.
// ws (floats): [0,1024) bsum | [1024,1664) sc | [2048, 2048+81920) ct[g][d][k]

// ---------------- prep: transpose codebook to [g][d][k] + codeword norms ---
__global__ void prep_kernel(const float* __restrict__ cb, float* __restrict__ sc,
                            float* __restrict__ ct) {
  int i = blockIdx.x * 256 + threadIdx.x;                 // 81920 total
  int g = i / (GD * NK), r = i % (GD * NK), d = r / NK, k = r % NK;
  ct[i] = cb[((size_t)g * NK + k) * GD + d];
  if (i < NG * NK) {
    const float* c = cb + (size_t)i * GD;
    float s = 0.f;
    for (int dd = 0; dd < GD; ++dd) s = fmaf(c[dd], c[dd], s);
    sc[i] = s;
  }
}

// ---------------- main: 512 thr, 8 waves x 20 codes, 4 tok/lane ------------
// x: LDS double-buffered (lgkmcnt). codes: VMEM loads at a wave-uniform but
// NOT provably-uniform address (w = tid>>6, no readfirstlane) -> 1 coalesced
// L1 request, vmcnt-counted -> decoupled from the ds_read stream. This breaks
// the per-dd lgkmcnt interlock (s_load is out-of-order on lgkm) that pinned
// r11/r13 at ~54% VALUBusy.
__global__ __launch_bounds__(512) void vq_kernel(const float* __restrict__ xin,
                                                 const float* __restrict__ cb,
                                                 const float* __restrict__ sc,
                                                 const float* __restrict__ ct,
                                                 float* __restrict__ out,
                                                 float* __restrict__ bsum) {
  __shared__ __align__(16) float xs[2][BK * BTOK];        // 64 KB
  __shared__ int kfS[BTOK];
  __shared__ float wred[4];

  const int tid = (int)threadIdx.x;
  const int w = tid >> 6;                                 // wave 0..7
  const int l = tid & 63;                                 // lane
  const int g = (int)(blockIdx.x >> 8);
  const int tb = (int)(blockIdx.x & 255);
  const int b = tb >> 4;
  const int t0 = (tb & 15) << 8;                          // 256-token window

  const float* xbase = xin + ((size_t)(b * ED + g * GD)) * TT + t0;
  const float* ctg = ct + (size_t)g * GD * NK;
  const int kbase = w * 20;    // divergent-typed -> VMEM path (no s_load)

  // prologue: stage slice 0 into xs[0]
  f32x4 st[4];
#pragma unroll
  for (int i = 0; i < 4; ++i) {
    int q = i * 512 + tid, dd = q >> 6, col = (q & 63) << 2;
    st[i] = *(const f32x4*)(xbase + (size_t)dd * TT + col);
  }
#pragma unroll
  for (int i = 0; i < 4; ++i) {
    int q = i * 512 + tid, dd = q >> 6, col = (q & 63) << 2;
    *(f32x4*)&xs[0][dd * BTOK + col] = st[i];
  }
  __syncthreads();

  float acc[4][20];
#pragma unroll
  for (int i = 0; i < 4; ++i)
#pragma unroll
    for (int j = 0; j < 20; ++j) acc[i][j] = 0.f;
  float sxa[4] = {0.f, 0.f, 0.f, 0.f};

  for (int s = 0; s < 4; ++s) {                           // 4 K-slices
    const int cur = s & 1;
    // issue next slice's x loads now; they ripen under this slice's compute
    if (s < 3) {
#pragma unroll
      for (int i = 0; i < 4; ++i) {
        int q = i * 512 + tid, dd = q >> 6, col = (q & 63) << 2;
        st[i] = *(const f32x4*)(xbase + (size_t)((s + 1) * BK + dd) * TT + col);
      }
    }
    // compute slice s from xs[cur]; codes via VMEM (vmcnt), x via DS (lgkm)
#pragma unroll 4
    for (int dd = 0; dd < BK; ++dd) {
      const f32x4 xv = *(const f32x4*)&xs[cur][dd * BTOK + l * 4];
      const float* cw = ctg + (size_t)(s * BK + dd) * NK + kbase;
      const f32x4 c0 = *(const f32x4*)&cw[0];
      const f32x4 c1 = *(const f32x4*)&cw[4];
      const f32x4 c2 = *(const f32x4*)&cw[8];
      const f32x4 c3 = *(const f32x4*)&cw[12];
      const f32x4 c4 = *(const f32x4*)&cw[16];
      // sx chain (ascending d, parity with r3-r13)
#pragma unroll
      for (int i = 0; i < 4; ++i) sxa[i] = fmaf(xv[i], xv[i], sxa[i]);
      // dot chains (ascending d per (i,j), parity with r3-r13)
#pragma unroll
      for (int i = 0; i < 4; ++i) {
        const float xf = xv[i];
#pragma unroll
        for (int e = 0; e < 4; ++e) {
          acc[i][e] = fmaf(xf, c0[e], acc[i][e]);
          acc[i][4 + e] = fmaf(xf, c1[e], acc[i][4 + e]);
          acc[i][8 + e] = fmaf(xf, c2[e], acc[i][8 + e]);
          acc[i][12 + e] = fmaf(xf, c3[e], acc[i][12 + e]);
          acc[i][16 + e] = fmaf(xf, c4[e], acc[i][16 + e]);
        }
      }
    }
    // write next slice into the other buffer; single barrier per slice
    if (s < 3) {
#pragma unroll
      for (int i = 0; i < 4; ++i) {
        int q = i * 512 + tid, dd = q >> 6, col = (q & 63) << 2;
        *(f32x4*)&xs[cur ^ 1][dd * BTOK + col] = st[i];
      }
      __syncthreads();
    }
  }

  // ---- per-wave argmin over its 20 codes (ascending k, strict <) ----
  const float* scw = sc + g * NK + kbase;
  float best[4] = {3.4e38f, 3.4e38f, 3.4e38f, 3.4e38f};
  int bik[4] = {0, 0, 0, 0};
#pragma unroll
  for (int j = 0; j < 20; ++j) {
    const float scv = scw[j];
#pragma unroll
    for (int i = 0; i < 4; ++i) {
      const float dv = (sxa[i] + scv) - 2.0f * acc[i][j]; // ref formula order
      if (dv < best[i]) { best[i] = dv; bik[i] = kbase + j; }
    }
  }

  // ---- cross-wave merge (reuse xs[0]) ----
  __syncthreads();                                        // slice-3 reads done
  float* bestW = xs[0];                                   // [8][256]
  int* bikW = (int*)xs[0] + 2048;                         // [8][256]
  *(f32x4*)&bestW[w * 256 + l * 4] = (f32x4){best[0], best[1], best[2], best[3]};
#pragma unroll
  for (int i = 0; i < 4; ++i) bikW[w * 256 + l * 4 + i] = bik[i];
  __syncthreads();

  if (tid < 256) {                                        // token owner = tid
    float bf = bestW[tid];
    int kf = bikW[tid];
#pragma unroll
    for (int ww = 1; ww < 8; ++ww) {                      // ascending k order
      float bw = bestW[ww * 256 + tid];
      int kw = bikW[ww * 256 + tid];
      if (bw < bf) { bf = bw; kf = kw; }                  // first-min kept
    }
    kfS[tid] = kf;

    // codes_out[b, g, t0+tid]
    out[ZSZ + 1 + ((size_t)(b * NG + g)) * TT + t0 + tid] = (float)kf;

    // loss partial: deterministic wave reduce (waves 0..3)
    float s = bf;
#pragma unroll
    for (int off = 32; off > 0; off >>= 1) s += __shfl_down(s, off, 64);
    if (l == 0) wred[w] = s;
  }
  __syncthreads();

  // ---- z_q write split across all 512 threads (half the d-range each) ----
  {
    const int tok = tid & 255;
    const int half = tid >> 8;                            // 0: d<64, 1: d>=64
    const int kf = kfS[tok];
    const f32x4* cw = (const f32x4*)(cb + ((size_t)g * NK + kf) * GD) + half * 16;
    float* zbase = out + ((size_t)(b * ED + g * GD) + (size_t)half * 64) * TT
                   + t0 + tok;
#pragma unroll 4
    for (int d4 = 0; d4 < 16; ++d4) {
      f32x4 v = cw[d4];
      zbase[(size_t)(4 * d4 + 0) * TT] = v[0];
      zbase[(size_t)(4 * d4 + 1) * TT] = v[1];
      zbase[(size_t)(4 * d4 + 2) * TT] = v[2];
      zbase[(size_t)(4 * d4 + 3) * TT] = v[3];
    }
  }

  if (tid == 0)
    bsum[blockIdx.x] = ((wred[0] + wred[1]) + wred[2]) + wred[3];
}

// ---------------- loss ----------------
__global__ __launch_bounds__(64) void loss_kernel(const float* __restrict__ bsum,
                                                  float* __restrict__ out) {
  float s = 0.f;
  for (int j = 0; j < 16; ++j) s += bsum[threadIdx.x + 64 * j];
#pragma unroll
  for (int off = 32; off > 0; off >>= 1) s += __shfl_down(s, off, 64);
  if (threadIdx.x == 0) out[ZSZ] = 1.25f * s / (float)ZSZ;
}

extern "C" void kernel_launch(void* const* d_in, const int* in_sizes, int n_in,
                              void* d_out, int out_size, void* d_ws, size_t ws_size,
                              hipStream_t stream) {
  const float* xin = (const float*)d_in[0];
  const float* cb  = (const float*)d_in[1];
  float* out  = (float*)d_out;
  float* bsum = (float*)d_ws;            // 1024
  float* sc   = (float*)d_ws + 1024;     // 640
  float* ct   = (float*)d_ws + 2048;     // 81920

  prep_kernel<<<320, 256, 0, stream>>>(cb, sc, ct);
  vq_kernel<<<1024, 512, 0, stream>>>(xin, cb, sc, ct, out, bsum);
  loss_kernel<<<1, 64, 0, stream>>>(bsum, out);
}

// Round 16
// 132.368 us; speedup vs baseline: 1.8156x; 1.8156x over previous
//
#include <hip/hip_runtime.h>
#include <stdint.h>

#define NG 4
#define NK 160
#define GD 128
#define ED 512
#define BB 16
#define TT 4096
#define BK 32
#define WTOK 128                     // tokens per block window
static constexpr size_t ZSZ = (size_t)BB * ED * TT;           // 33554432

typedef float f32x4 __attribute__((ext_vector_type(4)));
typedef float f32x2 __attribute__((ext_vector_type(2)));

// d_out FLOAT32: [0,ZSZ) z_q | [ZSZ] loss | codes after.
// ws (floats): [0,2048) bsum | [2048,2688) sc | [4096, 4096+81920) ct[g][d][k]

// ---------------- prep: transpose codebook to [g][d][k] + codeword norms ---
__global__ void prep_kernel(const float* __restrict__ cb, float* __restrict__ sc,
                            float* __restrict__ ct) {
  int i = blockIdx.x * 256 + threadIdx.x;                 // 81920 total
  int g = i / (GD * NK), r = i % (GD * NK), d = r / NK, k = r % NK;
  ct[i] = cb[((size_t)g * NK + k) * GD + d];
  if (i < NG * NK) {
    const float* c = cb + (size_t)i * GD;
    float s = 0.f;
    for (int dd = 0; dd < GD; ++dd) s = fmaf(c[dd], c[dd], s);
    sc[i] = s;
  }
}

// ---------------- main: 512 thr, 8 waves x 20 codes, 2 tok/lane ------------
// r11 structure (barrier-staged x, s_load codes) with HALF the register
// footprint: acc[2][20]=40 -> ~5 waves/SIMD so the per-dd lgkm drain
// (~150cy, irreducible at source level) is covered by TLP (5x84cy work).
__global__ __launch_bounds__(512) void vq_kernel(const float* __restrict__ xin,
                                                 const float* __restrict__ cb,
                                                 const float* __restrict__ sc,
                                                 const float* __restrict__ ct,
                                                 float* __restrict__ out,
                                                 float* __restrict__ bsum) {
  __shared__ __align__(16) float xs[BK * WTOK];           // 16 KB
  __shared__ int kfS[WTOK];
  __shared__ float wred[2];

  const int tid = (int)threadIdx.x;
  const int w = tid >> 6;                                 // wave 0..7
  const int l = tid & 63;                                 // lane
  const int g = (int)(blockIdx.x >> 9);                   // 512 blocks/group
  const int tb = (int)(blockIdx.x & 511);
  const int b = tb >> 5;
  const int t0 = (tb & 31) << 7;                          // 128-token window

  const float* xbase = xin + ((size_t)(b * ED + g * GD)) * TT + t0;
  const float* ctg = ct + (size_t)g * GD * NK;
  const int kbase = __builtin_amdgcn_readfirstlane(w) * 20;  // -> s_load path

  float acc[2][20];
#pragma unroll
  for (int i = 0; i < 2; ++i)
#pragma unroll
    for (int j = 0; j < 20; ++j) acc[i][j] = 0.f;
  float sxa[2] = {0.f, 0.f};

  for (int s = 0; s < 4; ++s) {                           // 4 K-slices
    __syncthreads();                                      // prev reads done
    // stage xs [BK][128]: 1024 f32x4, 2 per thread, coalesced along t
#pragma unroll
    for (int i = 0; i < 2; ++i) {
      int q = i * 512 + tid;
      int dd = q >> 5, col = (q & 31) << 2;
      *(f32x4*)&xs[dd * WTOK + col] =
          *(const f32x4*)(xbase + (size_t)(s * BK + dd) * TT + col);
    }
    __syncthreads();

#pragma unroll 4
    for (int dd = 0; dd < BK; ++dd) {
      const f32x2 xv = *(const f32x2*)&xs[dd * WTOK + l * 2];
      const float* cw = ctg + (size_t)(s * BK + dd) * NK + kbase;  // uniform
      const f32x4 c0 = *(const f32x4*)&cw[0];
      const f32x4 c1 = *(const f32x4*)&cw[4];
      const f32x4 c2 = *(const f32x4*)&cw[8];
      const f32x4 c3 = *(const f32x4*)&cw[12];
      const f32x4 c4 = *(const f32x4*)&cw[16];
      // sx chain (ascending d, parity with r3-r15)
#pragma unroll
      for (int i = 0; i < 2; ++i) sxa[i] = fmaf(xv[i], xv[i], sxa[i]);
      // dot chains (ascending d per (i,j), parity with r3-r15)
#pragma unroll
      for (int i = 0; i < 2; ++i) {
        const float xf = xv[i];
#pragma unroll
        for (int e = 0; e < 4; ++e) {
          acc[i][e] = fmaf(xf, c0[e], acc[i][e]);
          acc[i][4 + e] = fmaf(xf, c1[e], acc[i][4 + e]);
          acc[i][8 + e] = fmaf(xf, c2[e], acc[i][8 + e]);
          acc[i][12 + e] = fmaf(xf, c3[e], acc[i][12 + e]);
          acc[i][16 + e] = fmaf(xf, c4[e], acc[i][16 + e]);
        }
      }
    }
  }

  // ---- per-wave argmin over its 20 codes (ascending k, strict <) ----
  const float* scw = sc + g * NK + kbase;
  float best[2] = {3.4e38f, 3.4e38f};
  int bik[2] = {0, 0};
#pragma unroll
  for (int j = 0; j < 20; ++j) {
    const float scv = scw[j];
#pragma unroll
    for (int i = 0; i < 2; ++i) {
      const float dv = (sxa[i] + scv) - 2.0f * acc[i][j]; // ref formula order
      if (dv < best[i]) { best[i] = dv; bik[i] = kbase + j; }
    }
  }

  // ---- cross-wave merge (reuse xs) ----
  __syncthreads();                                        // k-loop reads done
  float* bestW = xs;                                      // [8][128]
  int* bikW = (int*)xs + 1024;                            // [8][128]
  *(f32x2*)&bestW[w * WTOK + l * 2] = (f32x2){best[0], best[1]};
  bikW[w * WTOK + l * 2] = bik[0];
  bikW[w * WTOK + l * 2 + 1] = bik[1];
  __syncthreads();

  if (tid < WTOK) {                                       // token owner = tid
    float bf = bestW[tid];
    int kf = bikW[tid];
#pragma unroll
    for (int ww = 1; ww < 8; ++ww) {                      // ascending k order
      float bw = bestW[ww * WTOK + tid];
      int kw = bikW[ww * WTOK + tid];
      if (bw < bf) { bf = bw; kf = kw; }                  // first-min kept
    }
    kfS[tid] = kf;

    // codes_out[b, g, t0+tid]
    out[ZSZ + 1 + ((size_t)(b * NG + g)) * TT + t0 + tid] = (float)kf;

    // loss partial: deterministic wave reduce (waves 0..1 hold tid<128)
    float s = bf;
#pragma unroll
    for (int off = 32; off > 0; off >>= 1) s += __shfl_down(s, off, 64);
    if (l == 0) wred[w] = s;
  }
  __syncthreads();

  // ---- z_q write split across all 512 threads (quarter d-range each) ----
  {
    const int tok = tid & 127;
    const int quarter = tid >> 7;                         // 0..3 -> d-block
    const int kf = kfS[tok];
    const f32x4* cw = (const f32x4*)(cb + ((size_t)g * NK + kf) * GD) + quarter * 8;
    float* zbase = out + ((size_t)(b * ED + g * GD) + (size_t)quarter * 32) * TT
                   + t0 + tok;
#pragma unroll 4
    for (int d4 = 0; d4 < 8; ++d4) {
      f32x4 v = cw[d4];
      zbase[(size_t)(4 * d4 + 0) * TT] = v[0];
      zbase[(size_t)(4 * d4 + 1) * TT] = v[1];
      zbase[(size_t)(4 * d4 + 2) * TT] = v[2];
      zbase[(size_t)(4 * d4 + 3) * TT] = v[3];
    }
  }

  if (tid == 0) bsum[blockIdx.x] = wred[0] + wred[1];
}

// ---------------- loss ----------------
__global__ __launch_bounds__(64) void loss_kernel(const float* __restrict__ bsum,
                                                  float* __restrict__ out) {
  float s = 0.f;
  for (int j = 0; j < 32; ++j) s += bsum[threadIdx.x + 64 * j];
#pragma unroll
  for (int off = 32; off > 0; off >>= 1) s += __shfl_down(s, off, 64);
  if (threadIdx.x == 0) out[ZSZ] = 1.25f * s / (float)ZSZ;
}

extern "C" void kernel_launch(void* const* d_in, const int* in_sizes, int n_in,
                              void* d_out, int out_size, void* d_ws, size_t ws_size,
                              hipStream_t stream) {
  const float* xin = (const float*)d_in[0];
  const float* cb  = (const float*)d_in[1];
  float* out  = (float*)d_out;
  float* bsum = (float*)d_ws;            // 2048
  float* sc   = (float*)d_ws + 2048;     // 640
  float* ct   = (float*)d_ws + 4096;     // 81920

  prep_kernel<<<320, 256, 0, stream>>>(cb, sc, ct);
  vq_kernel<<<2048, 512, 0, stream>>>(xin, cb, sc, ct, out, bsum);
  loss_kernel<<<1, 64, 0, stream>>>(bsum, out);
}